// Round 1
// baseline (5418.577 us; speedup 1.0000x reference)
//
#include <hip/hip_runtime.h>

// ODEModel: y0 = mean_T(x0[B,200,6]); 101 RK4 steps of 6->50->50->6 ReLU MLP.
// One thread per batch element. Weights read with wave-uniform indices from
// global (const __restrict__) so the compiler emits scalar loads (s_load) and
// the FMAs are v_fmac_f32 v,s,v -- VALU-bound by design.

#define D_IN   6
#define H_DIM  50
#define T_LEN  200

__device__ __forceinline__ void mlp_eval(
    const float* __restrict__ W1, const float* __restrict__ b1,
    const float* __restrict__ W2, const float* __restrict__ b2,
    const float* __restrict__ W3, const float* __restrict__ b3,
    const float y[D_IN], float k[D_IN])
{
    // layer 1: 6 -> 50, ReLU
    float h1[H_DIM];
#pragma unroll
    for (int j = 0; j < H_DIM; ++j) h1[j] = b1[j];
#pragma unroll
    for (int i = 0; i < D_IN; ++i) {
        float v = y[i];
#pragma unroll
        for (int j = 0; j < H_DIM; ++j) h1[j] = fmaf(v, W1[i * H_DIM + j], h1[j]);
    }
#pragma unroll
    for (int j = 0; j < H_DIM; ++j) h1[j] = fmaxf(h1[j], 0.0f);

    // layer 2: 50 -> 50 (ReLU applied at consumption in layer 3)
    float h2[H_DIM];
#pragma unroll
    for (int j = 0; j < H_DIM; ++j) h2[j] = b2[j];
#pragma unroll
    for (int i = 0; i < H_DIM; ++i) {
        float v = h1[i];
#pragma unroll
        for (int j = 0; j < H_DIM; ++j) h2[j] = fmaf(v, W2[i * H_DIM + j], h2[j]);
    }

    // layer 3: 50 -> 6
#pragma unroll
    for (int d = 0; d < D_IN; ++d) k[d] = b3[d];
#pragma unroll
    for (int i = 0; i < H_DIM; ++i) {
        float v = fmaxf(h2[i], 0.0f);
#pragma unroll
        for (int d = 0; d < D_IN; ++d) k[d] = fmaf(v, W3[i * D_IN + d], k[d]);
    }
}

extern "C" __global__ __launch_bounds__(256)
void ode_fused(const float* __restrict__ x0, const float* __restrict__ ts,
               const float* __restrict__ W1, const float* __restrict__ b1,
               const float* __restrict__ W2, const float* __restrict__ b2,
               const float* __restrict__ W3, const float* __restrict__ b3,
               float* __restrict__ out, int B, int nt)
{
    int b = blockIdx.x * blockDim.x + threadIdx.x;
    if (b >= B) return;

    // ---- phase 1: y0 = mean over T of x0[b, :, :] (1200 contiguous floats) ----
    const float4* xrow = (const float4*)(x0 + (size_t)b * (T_LEN * D_IN));
    float acc[D_IN];
#pragma unroll
    for (int d = 0; d < D_IN; ++d) acc[d] = 0.0f;

    // 1200 floats = 100 iterations x 3 float4 (12 floats = 2 full phase cycles)
#pragma unroll 4
    for (int c = 0; c < (T_LEN * D_IN) / 12; ++c) {
        float4 v0 = xrow[c * 3 + 0];
        float4 v1 = xrow[c * 3 + 1];
        float4 v2 = xrow[c * 3 + 2];
        acc[0] += v0.x + v1.z;
        acc[1] += v0.y + v1.w;
        acc[2] += v0.z + v2.x;
        acc[3] += v0.w + v2.y;
        acc[4] += v1.x + v2.z;
        acc[5] += v1.y + v2.w;
    }

    float y[D_IN];
#pragma unroll
    for (int d = 0; d < D_IN; ++d) y[d] = acc[d] * (1.0f / (float)T_LEN);

    // ---- phase 2: RK4 over nt-1 steps ----
#pragma unroll 1
    for (int s = 0; s < nt - 1; ++s) {
        float t0 = ts[s];
        float t1 = ts[s + 1];
        float dt = t1 - t0;

        float acck[D_IN];
        float yt[D_IN];
#pragma unroll
        for (int d = 0; d < D_IN; ++d) { acck[d] = 0.0f; yt[d] = y[d]; }

#pragma unroll 1
        for (int st = 0; st < 4; ++st) {
            float k[D_IN];
            mlp_eval(W1, b1, W2, b2, W3, b3, yt, k);
            float w = (st == 1 || st == 2) ? 2.0f : 1.0f;  // k weights 1,2,2,1
            float a = (st == 2) ? 1.0f : 0.5f;             // y-offset coeff 0.5,0.5,1,(dead)
#pragma unroll
            for (int d = 0; d < D_IN; ++d) {
                acck[d] = fmaf(w, k[d], acck[d]);
                yt[d]   = fmaf(a * dt, k[d], y[d]);
            }
        }
#pragma unroll
        for (int d = 0; d < D_IN; ++d) y[d] = fmaf(dt * (1.0f / 6.0f), acck[d], y[d]);
    }

    // ---- write y[-1] ----
    float* o = out + (size_t)b * D_IN;
#pragma unroll
    for (int d = 0; d < D_IN; ++d) o[d] = y[d];
}

extern "C" void kernel_launch(void* const* d_in, const int* in_sizes, int n_in,
                              void* d_out, int out_size, void* d_ws, size_t ws_size,
                              hipStream_t stream) {
    const float* x0 = (const float*)d_in[0];
    const float* ts = (const float*)d_in[1];
    const float* W1 = (const float*)d_in[2];
    const float* b1 = (const float*)d_in[3];
    const float* W2 = (const float*)d_in[4];
    const float* b2 = (const float*)d_in[5];
    const float* W3 = (const float*)d_in[6];
    const float* b3 = (const float*)d_in[7];
    float* out = (float*)d_out;

    int B  = in_sizes[0] / (T_LEN * D_IN);
    int nt = in_sizes[1];

    dim3 block(256);
    dim3 grid((B + 255) / 256);
    hipLaunchKernelGGL(ode_fused, grid, block, 0, stream,
                       x0, ts, W1, b1, W2, b2, W3, b3, out, B, nt);
}

// Round 2
// 4963.068 us; speedup vs baseline: 1.0918x; 1.0918x over previous
//
#include <hip/hip_runtime.h>
#include <cstdint>

// ODEModel: y0 = mean_T(x0[B,200,6]); 101 RK4 steps of 6->50->50->6 ReLU MLP.
// One thread per batch element (lane = batch). Weights are wave-uniform ->
// accessed through the CONSTANT address space (AS4) so the compiler emits
// s_load (scalar pipe, SGPR operands) and every FMA is v_fmac_f32 v,s,v.
// R1 fix: R0 compiled weight reads as per-lane flat loads (3 VALU addr ops
// per load -> 4x VALU bloat, 5250us). AS4 cast + uniform control flow
// (no early-exit) forces the scalar path.

#define D_IN   6
#define H_DIM  50
#define T_LEN  200

// constant-address-space pointer (scalar-load path). Cast through uintptr_t:
// AS4 addresses alias global addresses numerically on amdgcn.
typedef const float __attribute__((address_space(4)))* cfp;

__device__ __forceinline__ void mlp_eval(
    cfp W1, cfp b1, cfp W2, cfp b2, cfp W3, cfp b3,
    const float y[D_IN], float k[D_IN])
{
    // layer 1: 6 -> 50, ReLU
    float h1[H_DIM];
#pragma unroll
    for (int j = 0; j < H_DIM; ++j) h1[j] = b1[j];
#pragma unroll
    for (int i = 0; i < D_IN; ++i) {
        float v = y[i];
#pragma unroll
        for (int j = 0; j < H_DIM; ++j) h1[j] = fmaf(v, W1[i * H_DIM + j], h1[j]);
    }
#pragma unroll
    for (int j = 0; j < H_DIM; ++j) h1[j] = fmaxf(h1[j], 0.0f);

    // layer 2: 50 -> 50 (ReLU applied at consumption in layer 3)
    float h2[H_DIM];
#pragma unroll
    for (int j = 0; j < H_DIM; ++j) h2[j] = b2[j];
#pragma unroll
    for (int i = 0; i < H_DIM; ++i) {
        float v = h1[i];
#pragma unroll
        for (int j = 0; j < H_DIM; ++j) h2[j] = fmaf(v, W2[i * H_DIM + j], h2[j]);
    }

    // layer 3: 50 -> 6
#pragma unroll
    for (int d = 0; d < D_IN; ++d) k[d] = b3[d];
#pragma unroll
    for (int i = 0; i < H_DIM; ++i) {
        float v = fmaxf(h2[i], 0.0f);
#pragma unroll
        for (int d = 0; d < D_IN; ++d) k[d] = fmaf(v, W3[i * D_IN + d], k[d]);
    }
}

extern "C" __global__ __launch_bounds__(256)
void ode_fused(const float* __restrict__ x0, const float* __restrict__ ts_g,
               const float* __restrict__ W1g, const float* __restrict__ b1g,
               const float* __restrict__ W2g, const float* __restrict__ b2g,
               const float* __restrict__ W3g, const float* __restrict__ b3g,
               float* __restrict__ out, int nt)
{
    // NOTE: no bounds check -- grid*block == B exactly (B = 65536), keeps
    // control flow wave-uniform so scalar loads are legal everywhere.
    int b = blockIdx.x * blockDim.x + threadIdx.x;

    cfp W1 = (cfp)(uintptr_t)W1g;
    cfp b1 = (cfp)(uintptr_t)b1g;
    cfp W2 = (cfp)(uintptr_t)W2g;
    cfp b2 = (cfp)(uintptr_t)b2g;
    cfp W3 = (cfp)(uintptr_t)W3g;
    cfp b3 = (cfp)(uintptr_t)b3g;
    cfp ts = (cfp)(uintptr_t)ts_g;

    // ---- phase 1: y0 = mean over T of x0[b, :, :] (1200 contiguous floats) ----
    const float4* xrow = (const float4*)(x0 + (size_t)b * (T_LEN * D_IN));
    float acc[D_IN];
#pragma unroll
    for (int d = 0; d < D_IN; ++d) acc[d] = 0.0f;

    // 1200 floats = 100 iterations x 3 float4 (12 floats per iteration)
#pragma unroll 4
    for (int c = 0; c < (T_LEN * D_IN) / 12; ++c) {
        float4 v0 = xrow[c * 3 + 0];
        float4 v1 = xrow[c * 3 + 1];
        float4 v2 = xrow[c * 3 + 2];
        acc[0] += v0.x + v1.z;
        acc[1] += v0.y + v1.w;
        acc[2] += v0.z + v2.x;
        acc[3] += v0.w + v2.y;
        acc[4] += v1.x + v2.z;
        acc[5] += v1.y + v2.w;
    }

    float y[D_IN];
#pragma unroll
    for (int d = 0; d < D_IN; ++d) y[d] = acc[d] * (1.0f / (float)T_LEN);

    // ---- phase 2: RK4 over nt-1 steps ----
#pragma unroll 1
    for (int s = 0; s < nt - 1; ++s) {
        float t0 = ts[s];
        float t1 = ts[s + 1];
        float dt = t1 - t0;

        float acck[D_IN];
        float yt[D_IN];
#pragma unroll
        for (int d = 0; d < D_IN; ++d) { acck[d] = 0.0f; yt[d] = y[d]; }

#pragma unroll 1
        for (int st = 0; st < 4; ++st) {
            float k[D_IN];
            mlp_eval(W1, b1, W2, b2, W3, b3, yt, k);
            float w = (st == 1 || st == 2) ? 2.0f : 1.0f;  // k weights 1,2,2,1
            float a = (st == 2) ? 1.0f : 0.5f;             // y-offset coeff
#pragma unroll
            for (int d = 0; d < D_IN; ++d) {
                acck[d] = fmaf(w, k[d], acck[d]);
                yt[d]   = fmaf(a * dt, k[d], y[d]);
            }
        }
#pragma unroll
        for (int d = 0; d < D_IN; ++d) y[d] = fmaf(dt * (1.0f / 6.0f), acck[d], y[d]);
    }

    // ---- write y[-1] ----
    float* o = out + (size_t)b * D_IN;
#pragma unroll
    for (int d = 0; d < D_IN; ++d) o[d] = y[d];
}

extern "C" void kernel_launch(void* const* d_in, const int* in_sizes, int n_in,
                              void* d_out, int out_size, void* d_ws, size_t ws_size,
                              hipStream_t stream) {
    const float* x0 = (const float*)d_in[0];
    const float* ts = (const float*)d_in[1];
    const float* W1 = (const float*)d_in[2];
    const float* b1 = (const float*)d_in[3];
    const float* W2 = (const float*)d_in[4];
    const float* b2 = (const float*)d_in[5];
    const float* W3 = (const float*)d_in[6];
    const float* b3 = (const float*)d_in[7];
    float* out = (float*)d_out;

    int B  = in_sizes[0] / (T_LEN * D_IN);
    int nt = in_sizes[1];

    dim3 block(256);
    dim3 grid(B / 256);  // B = 65536, exact multiple -- no tail
    hipLaunchKernelGGL(ode_fused, grid, block, 0, stream,
                       x0, ts, W1, b1, W2, b2, W3, b3, out, nt);
}